// Round 11
// baseline (87.061 us; speedup 1.0000x reference)
//
#include <hip/hip_runtime.h>

#define N_Q  100000
#define N_M  5000
#define G    64
#define NC   (G * G)                 // 4096 cells
#define RMAX 4                       // ring cap; unresolved -> brute overflow
#define CS_OFF_B   64
#define SORT_OFF_B (CS_OFF_B + 16400)         // 16464 (cs: 4097*4, padded)
#define OVF_OFF_B  (SORT_OFF_B + N_M * 16)    // 96464
#define WS_NEED    (OVF_OFF_B + N_Q * 4)      // 496464 B

// ============================================================================
// build_grid: bbox -> histogram -> scan -> scatter {x,y,ts,idx}. One 1024-thr
// block, shuffle-based reductions/scans -> only 4 barriers (the old version's
// ~60 barriers cost ~15 us). Box = actual min/max, inflated cell width ->
// every point provably inside its cell rect (ring bound proof). Scatter order
// nondeterministic; queries use order-free (d2,idx) lex-min -> deterministic.
// ============================================================================
__global__ __launch_bounds__(1024) void build_grid(
    const float* __restrict__ maze, const float* __restrict__ ts,
    float* __restrict__ ws)
{
    __shared__ int   cnt[NC];        // 16 KB
    __shared__ float wred[16][4];
    __shared__ int   wsum[16];
    const int t = threadIdx.x, lane = t & 63, wv = t >> 6;
    if (t == 0) ((int*)ws)[8] = 0;   // reset overflow counter (every call)

    // ---- bbox (wave shuffle reduce), zero histogram in parallel
    float mnx = 1e30f, mxx = -1e30f, mny = 1e30f, mxy = -1e30f;
    for (int i = t; i < N_M; i += 1024) {
        const float x = maze[2 * i], y = maze[2 * i + 1];
        mnx = fminf(mnx, x); mxx = fmaxf(mxx, x);
        mny = fminf(mny, y); mxy = fmaxf(mxy, y);
    }
    #pragma unroll
    for (int s = 1; s < 64; s <<= 1) {
        mnx = fminf(mnx, __shfl_xor(mnx, s));
        mxx = fmaxf(mxx, __shfl_xor(mxx, s));
        mny = fminf(mny, __shfl_xor(mny, s));
        mxy = fmaxf(mxy, __shfl_xor(mxy, s));
    }
    if (lane == 0) { wred[wv][0] = mnx; wred[wv][1] = mxx; wred[wv][2] = mny; wred[wv][3] = mxy; }
    for (int i = t; i < NC; i += 1024) cnt[i] = 0;
    __syncthreads();                                   // barrier 1
    #pragma unroll
    for (int w = 0; w < 16; ++w) {                     // per-thread recompute
        mnx = fminf(mnx, wred[w][0]); mxx = fmaxf(mxx, wred[w][1]);
        mny = fminf(mny, wred[w][2]); mxy = fmaxf(mxy, wred[w][3]);
    }
    float cwx = (mxx - mnx) * (1.0f / G) * (1.0f + 1e-5f);
    float cwy = (mxy - mny) * (1.0f / G) * (1.0f + 1e-5f);
    if (!(cwx > 0.0f)) cwx = 1.0f;                     // degenerate box
    if (!(cwy > 0.0f)) cwy = 1.0f;
    const float ivx = 1.0f / cwx, ivy = 1.0f / cwy;
    if (t == 0) { ws[0] = mnx; ws[1] = mny; ws[2] = cwx; ws[3] = cwy; ws[4] = ivx; ws[5] = ivy; }

    // ---- histogram
    for (int i = t; i < N_M; i += 1024) {
        const float x = maze[2 * i], y = maze[2 * i + 1];
        const int cx = min(G - 1, max(0, (int)((x - mnx) * ivx)));
        const int cy = min(G - 1, max(0, (int)((y - mny) * ivy)));
        atomicAdd(&cnt[cy * G + cx], 1);
    }
    __syncthreads();                                   // barrier 2

    // ---- exclusive scan: 4 cells/thread, shfl_up wave scan, 16 wave sums
    int* cs = (int*)((char*)ws + CS_OFF_B);
    const int base = t * 4;
    int loc[4], sum = 0;
    #pragma unroll
    for (int j = 0; j < 4; ++j) { loc[j] = sum; sum += cnt[base + j]; }
    int incl = sum;
    #pragma unroll
    for (int s = 1; s < 64; s <<= 1) {
        const int o = __shfl_up(incl, s);
        if (lane >= s) incl += o;
    }
    if (lane == 63) wsum[wv] = incl;
    __syncthreads();                                   // barrier 3
    int wbase = 0;
    for (int w = 0; w < 16; ++w) wbase += (w < wv) ? wsum[w] : 0;
    const int excl = wbase + incl - sum;
    #pragma unroll
    for (int j = 0; j < 4; ++j) cs[base + j] = excl + loc[j];
    if (t == 0) cs[NC] = N_M;
    #pragma unroll
    for (int j = 0; j < 4; ++j) cnt[base + j] = excl + loc[j];   // cursors
    __syncthreads();                                   // barrier 4

    // ---- scatter
    float4* sorted = (float4*)((char*)ws + SORT_OFF_B);
    for (int i = t; i < N_M; i += 1024) {
        const float x = maze[2 * i], y = maze[2 * i + 1];
        const int cx = min(G - 1, max(0, (int)((x - mnx) * ivx)));
        const int cy = min(G - 1, max(0, (int)((y - mny) * ivy)));
        const int pos = atomicAdd(&cnt[cy * G + cx], 1);
        float4 e; e.x = x; e.y = y; e.z = ts[i]; e.w = __int_as_float(i);
        sorted[pos] = e;
    }
}

// ============================================================================
// grid_query: stage cs (16.4 KB) + sorted (80 KB) into LDS (96.4 KB < 160 KB,
// 1 block/CU), then ring scans read ds_read instead of global gathers
// (~120 cy per round vs ~600-1000 effective). Ring cap RMAX; unresolved ->
// overflow list. Exact numpy IEEE sequence; (d2, orig_idx) lex-min is
// visit-order-free and duplicate-tolerant -> deterministic, bit-exact.
// ============================================================================
__global__ __launch_bounds__(256) void grid_query(
    const float* __restrict__ q, const float* __restrict__ maze,
    const float* __restrict__ ts, float* __restrict__ ws,
    float* __restrict__ out)
{
    __shared__ int    lcs[NC + 1];   // 16388 B
    __shared__ float4 lpt[N_M];      // 80000 B

    const int*    gcs = (const int*)((const char*)ws + CS_OFF_B);
    const float4* gpt = (const float4*)((const char*)ws + SORT_OFF_B);
    for (int i = threadIdx.x; i < NC + 1; i += 256) lcs[i] = gcs[i];
    for (int i = threadIdx.x; i < N_M; i += 256)    lpt[i] = gpt[i];

    const int qi = blockIdx.x * 256 + threadIdx.x;
    const int qc = qi < N_Q ? qi : N_Q - 1;
    const float mnx = ws[0], mny = ws[1], cwx = ws[2];
    const float cwy = ws[3], ivx = ws[4], ivy = ws[5];
    const float2 Q = ((const float2*)q)[qc];
    const float qx = Q.x, qy = Q.y;
    const int cx = min(G - 1, max(0, (int)((qx - mnx) * ivx)));
    const int cy = min(G - 1, max(0, (int)((qy - mny) * ivy)));
    __syncthreads();

    float bd2 = 3.4e38f;
    int bidx = 0x7fffffff;

    auto cand = [&](const float4 c) {
        const float dx = __fsub_rn(qx, c.x);       // numpy-exact, no FMA
        const float dy = __fsub_rn(qy, c.y);
        const float d2 = __fadd_rn(__fmul_rn(dx, dx), __fmul_rn(dy, dy));
        const int idx = __float_as_int(c.w);
        if (d2 < bd2 || (d2 == bd2 && idx < bidx)) { bd2 = d2; bidx = idx; }
    };
    auto scan8 = [&](int s, int e) {               // 8 ds_reads in flight
        for (int p = s; p < e; p += 8) {
            const float4 c0 = lpt[p];
            const float4 c1 = lpt[p + 1 < e ? p + 1 : p];
            const float4 c2 = lpt[p + 2 < e ? p + 2 : p];
            const float4 c3 = lpt[p + 3 < e ? p + 3 : p];
            const float4 c4 = lpt[p + 4 < e ? p + 4 : p];
            const float4 c5 = lpt[p + 5 < e ? p + 5 : p];
            const float4 c6 = lpt[p + 6 < e ? p + 6 : p];
            const float4 c7 = lpt[p + 7 < e ? p + 7 : p];
            cand(c0); cand(c1); cand(c2); cand(c3);
            cand(c4); cand(c5); cand(c6); cand(c7);
        }
    };
    auto bound_ok = [&](int r) -> bool {
        const float Xlo = mnx + (float)(cx - r) * cwx;
        const float Xhi = mnx + (float)(cx + r + 1) * cwx;
        const float Ylo = mny + (float)(cy - r) * cwy;
        const float Yhi = mny + (float)(cy + r + 1) * cwy;
        float lb = fminf(fminf(qx - Xlo, Xhi - qx), fminf(qy - Ylo, Yhi - qy));
        lb = lb * 0.9999f - 1e-6f;                 // >1-ulp conservative slack
        return (lb > 0.0f) && (lb * lb > bd2);
    };

    // ---- 3x3 box: one contiguous span per row
    {
        const int x0 = max(0, cx - 1), x1 = min(G - 1, cx + 1);
        const int rA = max(0, cy - 1) * G, rB = cy * G, rC = min(G - 1, cy + 1) * G;
        scan8(lcs[rA + x0], lcs[rA + x1 + 1]);
        scan8(lcs[rB + x0], lcs[rB + x1 + 1]);
        scan8(lcs[rC + x0], lcs[rC + x1 + 1]);
    }
    bool resolved = bound_ok(1);

    // ---- rings r=2..RMAX
    for (int r = 2; r <= RMAX && __any(!resolved); ++r) {
        if (!resolved) {
            const int X0 = max(0, cx - r), X1 = min(G - 1, cx + r);
            if (cy - r >= 0)     { const int rb = (cy - r) * G; scan8(lcs[rb + X0], lcs[rb + X1 + 1]); }
            if (cy + r <= G - 1) { const int rb = (cy + r) * G; scan8(lcs[rb + X0], lcs[rb + X1 + 1]); }
            const int Y0 = max(0, cy - r + 1), Y1 = min(G - 1, cy + r - 1);
            if (cx - r >= 0)     for (int y = Y0; y <= Y1; ++y) { const int c0 = y * G + cx - r; scan8(lcs[c0], lcs[c0 + 1]); }
            if (cx + r <= G - 1) for (int y = Y0; y <= Y1; ++y) { const int c0 = y * G + cx + r; scan8(lcs[c0], lcs[c0 + 1]); }
            resolved = bound_ok(r);
        }
    }

    if (qi < N_Q) {
        if (resolved) {
            out[2 * qi]       = maze[2 * bidx];
            out[2 * qi + 1]   = maze[2 * bidx + 1];
            out[2 * N_Q + qi] = ts[bidx];
        } else {
            int* ovfc = (int*)ws + 8;
            const int pos = atomicAdd(ovfc, 1);
            ((int*)((char*)ws + OVF_OFF_B))[pos] = qi;
        }
    }
}

// ============================================================================
// brute_overflow: one wave per unresolved query (grid-stride). Identical IEEE
// sequence, lex shuffle-reduce. Each query writes only its own slot.
// ============================================================================
__global__ __launch_bounds__(256) void brute_overflow(
    const float* __restrict__ q, const float* __restrict__ maze,
    const float* __restrict__ ts, const float* __restrict__ ws,
    float* __restrict__ out)
{
    const int cnt = ((const int*)ws)[8];
    const int* ovl = (const int*)((const char*)ws + OVF_OFF_B);
    const int wave  = (blockIdx.x * 256 + threadIdx.x) >> 6;
    const int lane  = threadIdx.x & 63;
    const int nwave = gridDim.x * 4;

    for (int w = wave; w < cnt; w += nwave) {
        const int qi = ovl[w];
        const float qx = q[2 * qi], qy = q[2 * qi + 1];
        float bd2 = 3.4e38f; int bidx = 0x7fffffff;
        for (int p = lane; p < N_M; p += 64) {
            const float2 c = ((const float2*)maze)[p];
            const float dx = __fsub_rn(qx, c.x);
            const float dy = __fsub_rn(qy, c.y);
            const float d2 = __fadd_rn(__fmul_rn(dx, dx), __fmul_rn(dy, dy));
            if (d2 < bd2 || (d2 == bd2 && p < bidx)) { bd2 = d2; bidx = p; }
        }
        #pragma unroll
        for (int s = 1; s < 64; s <<= 1) {
            const float ob = __shfl_xor(bd2, s);
            const int   oi = __shfl_xor(bidx, s);
            if (ob < bd2 || (ob == bd2 && oi < bidx)) { bd2 = ob; bidx = oi; }
        }
        if (lane == 0) {
            out[2 * qi]       = maze[2 * bidx];
            out[2 * qi + 1]   = maze[2 * bidx + 1];
            out[2 * N_Q + qi] = ts[bidx];
        }
    }
}

// ============================================================================
// Fallback: proven R5 SMEM-stream scan (66 us) if ws is too small.
// ============================================================================
#define CW   4
#define CHK  1264
#define NPAD (CW * CHK)

typedef float v2f __attribute__((ext_vector_type(2)));
typedef float v8f __attribute__((ext_vector_type(8)));

__global__ void setup_soa(const float* __restrict__ maze, float* __restrict__ ws) {
    const int i = blockIdx.x * 256 + threadIdx.x;
    if (i >= NPAD) return;
    const int c = i / CHK, k = i - c * CHK;
    float x = 1e30f, y = 1e30f;
    const int g = c * 1250 + k;
    if (k < 1250) { x = -maze[2 * g]; y = -maze[2 * g + 1]; }
    ws[i] = x;
    ws[NPAD + i] = y;
}

#define LDX0(D) asm volatile("s_load_dwordx8 %0, %1, 0x0"    : "=s"(D) : "s"(xb))
#define LDX1(D) asm volatile("s_load_dwordx8 %0, %1, 0x20"   : "=s"(D) : "s"(xb))
#define LDY0(D) asm volatile("s_load_dwordx8 %0, %1, 0x4f00" : "=s"(D) : "s"(xb))
#define LDY1(D) asm volatile("s_load_dwordx8 %0, %1, 0x4f20" : "=s"(D) : "s"(xb))
#define WAIT4(a,b,c,d) asm volatile("s_waitcnt lgkmcnt(0)" : "+s"(a), "+s"(b), "+s"(c), "+s"(d))

#define PSTEP(X8, Y8, J) do {                                                 \
    v2f px_ = __builtin_shufflevector(X8, X8, 2*(J), 2*(J)+1);                \
    v2f py_ = __builtin_shufflevector(Y8, Y8, 2*(J), 2*(J)+1);                \
    v2f dx_, dy_;                                                             \
    asm("v_pk_add_f32 %0, %1, %2" : "=v"(dx_) : "s"(px_), "v"(qxx));          \
    asm("v_pk_add_f32 %0, %1, %2" : "=v"(dy_) : "s"(py_), "v"(qyy));          \
    asm("v_pk_mul_f32 %0, %0, %0" : "+v"(dx_));                               \
    asm("v_pk_mul_f32 %0, %0, %0" : "+v"(dy_));                               \
    asm("v_pk_add_f32 %0, %0, %1" : "+v"(dx_) : "v"(dy_));                    \
    float a_ = dx_.x, b_ = dx_.y;                                             \
    asm("v_min3_f32 %0, %1, %2, %0" : "+v"(bm) : "v"(a_), "v"(b_));           \
} while (0)

#define COMP(X0, X1, Y0, Y1, B) do {                                          \
    PSTEP(X0, Y0, 0); PSTEP(X0, Y0, 1); PSTEP(X0, Y0, 2); PSTEP(X0, Y0, 3);   \
    PSTEP(X1, Y1, 0); PSTEP(X1, Y1, 1); PSTEP(X1, Y1, 2); PSTEP(X1, Y1, 3);   \
    bb = (bm < prev) ? (B) : bb; prev = bm;                                   \
} while (0)

__global__ __launch_bounds__(256) void nn_scan(
    const float* __restrict__ q, const float* __restrict__ maze,
    const float* __restrict__ ts, const float* __restrict__ ws,
    float* __restrict__ out)
{
    __shared__ float sval[CW][64];
    __shared__ int   sidx[CW][64];
    const int lane = threadIdx.x & 63;
    const int wv   = __builtin_amdgcn_readfirstlane((int)(threadIdx.x >> 6));
    const int qi   = blockIdx.x * 64 + lane;
    const int qc   = qi < N_Q ? qi : N_Q - 1;
    const float2 Q = ((const float2*)q)[qc];
    const v2f qxx = { Q.x, Q.x };
    const v2f qyy = { Q.y, Q.y };
    unsigned long long xb = (unsigned long long)(const void*)(ws + (size_t)wv * CHK);
    v8f ax0, ax1, ay0, ay1, bx0, bx1, by0, by1;
    LDX0(ax0); LDX1(ax1); LDY0(ay0); LDY1(ay1); xb += 64;
    float bm = 3.4e38f, prev = 3.4e38f;
    int bb = 0;
    #pragma unroll 1
    for (int k = 0; k < 39; ++k) {
        WAIT4(ax0, ax1, ay0, ay1);
        LDX0(bx0); LDX1(bx1); LDY0(by0); LDY1(by1); xb += 64;
        COMP(ax0, ax1, ay0, ay1, 2 * k);
        WAIT4(bx0, bx1, by0, by1);
        LDX0(ax0); LDX1(ax1); LDY0(ay0); LDY1(ay1); xb += 64;
        COMP(bx0, bx1, by0, by1, 2 * k + 1);
    }
    WAIT4(ax0, ax1, ay0, ay1);
    COMP(ax0, ax1, ay0, ay1, 78);
    int fk = 0x7fffffff;
    {
        const float* xs = ws + (size_t)wv * CHK + (size_t)bb * 16;
        #pragma unroll
        for (int j = 0; j < 16; ++j) {
            const float dx = __fadd_rn(Q.x, xs[j]);
            const float dy = __fadd_rn(Q.y, xs[j + NPAD]);
            const float d2 = __fadd_rn(__fmul_rn(dx, dx), __fmul_rn(dy, dy));
            if (d2 == bm) fk = min(fk, bb * 16 + j);
        }
    }
    const int kloc = fk < 1250 ? fk : 1249;
    sval[wv][lane] = bm;
    sidx[wv][lane] = wv * 1250 + kloc;
    __syncthreads();
    if (wv == 0 && qi < N_Q) {
        float bv = sval[0][lane];
        int   bg = sidx[0][lane];
        #pragma unroll
        for (int c = 1; c < CW; ++c) {
            const float v = sval[c][lane];
            const int   g = sidx[c][lane];
            if (v < bv || (v == bv && g < bg)) { bv = v; bg = g; }
        }
        const float2 bp = ((const float2*)maze)[bg];
        out[2 * qi]       = bp.x;
        out[2 * qi + 1]   = bp.y;
        out[2 * N_Q + qi] = ts[bg];
    }
}

extern "C" void kernel_launch(void* const* d_in, const int* in_sizes, int n_in,
                              void* d_out, int out_size, void* d_ws, size_t ws_size,
                              hipStream_t stream) {
    const float* q    = (const float*)d_in[0];  // euclidean_data [N,2]
    const float* maze = (const float*)d_in[1];  // maze_points   [M,2]
    const float* ts   = (const float*)d_in[2];  // ts_proj       [M]
    float* out = (float*)d_out;                 // [N*2] proj_pos ++ [N] linear_pos

    if (ws_size >= (size_t)WS_NEED) {
        build_grid<<<1, 1024, 0, stream>>>(maze, ts, (float*)d_ws);
        grid_query<<<(N_Q + 255) / 256, 256, 0, stream>>>(q, maze, ts,
                                                          (float*)d_ws, out);
        brute_overflow<<<128, 256, 0, stream>>>(q, maze, ts, (const float*)d_ws, out);
    } else {
        setup_soa<<<(NPAD + 255) / 256, 256, 0, stream>>>(maze, (float*)d_ws);
        nn_scan<<<(N_Q + 63) / 64, 256, 0, stream>>>(q, maze, ts,
                                                     (const float*)d_ws, out);
    }
}